// Round 1
// baseline (594.761 us; speedup 1.0000x reference)
//
#include <hip/hip_runtime.h>
#include <hip/hip_bf16.h>

#define NB 8
#define LQ 512
#define LK 2048
#define EE 512
#define NH 8
#define HD 64
#define NTOPK 20

typedef float f4v __attribute__((ext_vector_type(4)));
typedef short s4v __attribute__((ext_vector_type(4)));
typedef short s8v __attribute__((ext_vector_type(8)));
typedef __bf16 bfrag __attribute__((ext_vector_type(8)));

__device__ inline short f2bf(float f) {
    union { float f; unsigned u; } x; x.f = f;
    unsigned r = (x.u + 0x7FFFu + ((x.u >> 16) & 1u)) >> 16;
    return (short)r;
}

// C[M][512] = A[M][512] @ W[512][512]^T  (+ optional bias/residual)
// MODE 0: store bf16; MODE 1: store f32; MODE 2: store f32 + bias + resid
template<int MODE>
__global__ __launch_bounds__(256) void proj_gemm(
    const float* __restrict__ A, const float* __restrict__ W,
    void* __restrict__ C, const float* __restrict__ bias,
    const float* __restrict__ resid)
{
    __shared__ short As[128][40];   // +8 pad: 80B row stride, 16B aligned
    __shared__ short Bs[128][40];
    const int tid  = threadIdx.x;
    const int lane = tid & 63;
    const int wr   = (tid >> 7) & 1;
    const int wc   = (tid >> 6) & 1;
    const size_t bm = (size_t)blockIdx.y * 128;
    const int    bn = blockIdx.x * 128;

    f4v acc[4][4] = {};
    const int lr = lane & 15;
    const int kg = (lane >> 4) * 8;

    for (int ks = 0; ks < EE; ks += 32) {
        #pragma unroll
        for (int i = 0; i < 4; i++) {
            const int row = i * 32 + (tid >> 3);
            const int c4  = (tid & 7) * 4;
            f4v av = *(const f4v*)&A[(bm + row) * EE + ks + c4];
            f4v wv = *(const f4v*)&W[(size_t)(bn + row) * EE + ks + c4];
            s4v as, wsv;
            as[0] = f2bf(av[0]); as[1] = f2bf(av[1]);
            as[2] = f2bf(av[2]); as[3] = f2bf(av[3]);
            wsv[0] = f2bf(wv[0]); wsv[1] = f2bf(wv[1]);
            wsv[2] = f2bf(wv[2]); wsv[3] = f2bf(wv[3]);
            *(s4v*)&As[row][c4] = as;
            *(s4v*)&Bs[row][c4] = wsv;
        }
        __syncthreads();
        bfrag af[4], bfr[4];
        #pragma unroll
        for (int mi = 0; mi < 4; mi++)
            af[mi] = *(const bfrag*)&As[wr * 64 + mi * 16 + lr][kg];
        #pragma unroll
        for (int ni = 0; ni < 4; ni++)
            bfr[ni] = *(const bfrag*)&Bs[wc * 64 + ni * 16 + lr][kg];
        #pragma unroll
        for (int mi = 0; mi < 4; mi++)
            #pragma unroll
            for (int ni = 0; ni < 4; ni++)
                acc[mi][ni] = __builtin_amdgcn_mfma_f32_16x16x32_bf16(
                    af[mi], bfr[ni], acc[mi][ni], 0, 0, 0);
        __syncthreads();
    }

    const int rj = (lane >> 4) * 4;
    #pragma unroll
    for (int mi = 0; mi < 4; mi++) {
        #pragma unroll
        for (int ni = 0; ni < 4; ni++) {
            const int    col  = bn + wc * 64 + ni * 16 + lr;
            const size_t row0 = bm + wr * 64 + mi * 16 + rj;
            #pragma unroll
            for (int j = 0; j < 4; j++) {
                const float  v   = acc[mi][ni][j];
                const size_t idx = (row0 + j) * EE + col;
                if (MODE == 0)      ((short*)C)[idx] = f2bf(v);
                else if (MODE == 1) ((float*)C)[idx] = v;
                else                ((float*)C)[idx] = v + bias[col] + resid[idx];
            }
        }
    }
}

// S[h][m][n] = (1/8) * sum_k Qp[b][m][h*64+k] * Kp[b][n][h*64+k]   (one batch)
__global__ __launch_bounds__(256) void score_gemm(
    const short* __restrict__ Qp, const short* __restrict__ Kp,
    float* __restrict__ S, int b)
{
    __shared__ short As[128][72];   // 64 + 8 pad: 144B stride
    __shared__ short Bs[128][72];
    const int tid  = threadIdx.x;
    const int lane = tid & 63;
    const int wr   = (tid >> 7) & 1;
    const int wc   = (tid >> 6) & 1;
    const int h  = blockIdx.z;
    const int bm = blockIdx.y * 128;
    const int bn = blockIdx.x * 128;

    const short* Ab = Qp + (size_t)b * LQ * EE + h * HD;
    const short* Bb = Kp + (size_t)b * LK * EE + h * HD;

    #pragma unroll
    for (int i = 0; i < 4; i++) {
        const int row = i * 32 + (tid >> 3);
        const int c8  = (tid & 7) * 8;
        *(s8v*)&As[row][c8] = *(const s8v*)&Ab[(size_t)(bm + row) * EE + c8];
        *(s8v*)&Bs[row][c8] = *(const s8v*)&Bb[(size_t)(bn + row) * EE + c8];
    }
    __syncthreads();

    f4v acc[4][4] = {};
    const int lr = lane & 15;
    const int kg = (lane >> 4) * 8;
    #pragma unroll
    for (int kk = 0; kk < HD; kk += 32) {
        bfrag af[4], bfr[4];
        #pragma unroll
        for (int mi = 0; mi < 4; mi++)
            af[mi] = *(const bfrag*)&As[wr * 64 + mi * 16 + lr][kk + kg];
        #pragma unroll
        for (int ni = 0; ni < 4; ni++)
            bfr[ni] = *(const bfrag*)&Bs[wc * 64 + ni * 16 + lr][kk + kg];
        #pragma unroll
        for (int mi = 0; mi < 4; mi++)
            #pragma unroll
            for (int ni = 0; ni < 4; ni++)
                acc[mi][ni] = __builtin_amdgcn_mfma_f32_16x16x32_bf16(
                    af[mi], bfr[ni], acc[mi][ni], 0, 0, 0);
    }

    float* Sh = S + (size_t)h * LQ * LK;
    const int rj = (lane >> 4) * 4;
    #pragma unroll
    for (int mi = 0; mi < 4; mi++) {
        #pragma unroll
        for (int ni = 0; ni < 4; ni++) {
            const int col = bn + wc * 64 + ni * 16 + lr;
            const int r0  = bm + wr * 64 + mi * 16 + rj;
            #pragma unroll
            for (int j = 0; j < 4; j++)
                Sh[(size_t)(r0 + j) * LK + col] = acc[mi][ni][j] * 0.125f;
        }
    }
}

// one wave per query row: softmax stats over 2048 keys, top-20, fused PV
__global__ __launch_bounds__(256) void topk_pv(
    const float* __restrict__ S, const float* __restrict__ Vp,
    float* __restrict__ attn, int b)
{
    __shared__ float sc[4][LK];
    const int lane = threadIdx.x & 63;
    const int wid  = threadIdx.x >> 6;
    const int r  = blockIdx.x * 4 + wid;     // 0..4095 within this batch
    const int h  = r >> 9;
    const int qi = r & 511;
    const float* Srow = S + (size_t)r * LK;

    f4v vv[8];
    float vmax = -1e30f;
    #pragma unroll
    for (int t = 0; t < 8; t++) {
        const int j = t * 256 + lane * 4;
        vv[t] = *(const f4v*)&Srow[j];
        *(f4v*)&sc[wid][j] = vv[t];
        vmax = fmaxf(vmax, fmaxf(fmaxf(vv[t][0], vv[t][1]), fmaxf(vv[t][2], vv[t][3])));
    }
    #pragma unroll
    for (int o = 32; o; o >>= 1) vmax = fmaxf(vmax, __shfl_xor(vmax, o));

    float sum = 0.f;
    #pragma unroll
    for (int t = 0; t < 8; t++)
        sum += __expf(vv[t][0] - vmax) + __expf(vv[t][1] - vmax)
             + __expf(vv[t][2] - vmax) + __expf(vv[t][3] - vmax);
    #pragma unroll
    for (int o = 32; o; o >>= 1) sum += __shfl_xor(sum, o);
    const float inv = 1.f / sum;

    float oacc = 0.f;
    const float* Vb = Vp + (size_t)b * LK * EE + h * HD + lane;
    for (int kk = 0; kk < NTOPK; kk++) {
        float bv = -1e30f; int bi = 0;
        for (int t = 0; t < 32; t++) {
            const int j = t * 64 + lane;          // conflict-free column scan
            const float v = sc[wid][j];
            if (v > bv) { bv = v; bi = j; }
        }
        #pragma unroll
        for (int o = 32; o; o >>= 1) {
            const float ov = __shfl_xor(bv, o);
            const int   oi = __shfl_xor(bi, o);
            if (ov > bv || (ov == bv && oi < bi)) { bv = ov; bi = oi; }
        }
        if ((bi & 63) == lane) sc[wid][bi] = -1e30f;   // remove winner (own column)
        const float p = __expf(bv - vmax) * inv;
        oacc += p * Vb[(size_t)bi * EE];
    }
    attn[((size_t)b * LQ + qi) * EE + h * HD + lane] = oacc;
}

extern "C" void kernel_launch(void* const* d_in, const int* in_sizes, int n_in,
                              void* d_out, int out_size, void* d_ws, size_t ws_size,
                              hipStream_t stream)
{
    const float* q  = (const float*)d_in[0];
    const float* k  = (const float*)d_in[1];
    const float* v  = (const float*)d_in[2];
    const float* Wq = (const float*)d_in[3];
    const float* Wk = (const float*)d_in[4];
    const float* Wv = (const float*)d_in[5];
    const float* Wo = (const float*)d_in[6];
    const float* bo = (const float*)d_in[7];

    if (ws_size < (size_t)92 * 1024 * 1024) return;  // need 92 MiB scratch

    char*  ws   = (char*)d_ws;
    short* Qp   = (short*)(ws);                          //  4 MiB bf16 [8,512,512]
    short* Kp   = (short*)(ws + ((size_t)4  << 20));     // 16 MiB bf16 [8,2048,512]
    float* Vp   = (float*)(ws + ((size_t)20 << 20));     // 32 MiB f32  [8,2048,512]
    float* attn = (float*)(ws + ((size_t)52 << 20));     //  8 MiB f32  [8,512,512]
    float* Sb   = (float*)(ws + ((size_t)60 << 20));     // 32 MiB f32  [8,512,2048] (per batch)

    dim3 blk(256);
    proj_gemm<0><<<dim3(4, LQ * NB / 128), blk, 0, stream>>>(q, Wq, Qp, nullptr, nullptr);
    proj_gemm<0><<<dim3(4, LK * NB / 128), blk, 0, stream>>>(k, Wk, Kp, nullptr, nullptr);
    proj_gemm<1><<<dim3(4, LK * NB / 128), blk, 0, stream>>>(v, Wv, Vp, nullptr, nullptr);

    for (int b = 0; b < NB; b++) {
        score_gemm<<<dim3(LK / 128, LQ / 128, NH), blk, 0, stream>>>(Qp, Kp, Sb, b);
        topk_pv<<<dim3(NH * LQ / 4), blk, 0, stream>>>(Sb, Vp, attn, b);
    }

    proj_gemm<2><<<dim3(4, LQ * NB / 128), blk, 0, stream>>>(attn, Wo, (float*)d_out, bo, q);
}

// Round 2
// 486.727 us; speedup vs baseline: 1.2220x; 1.2220x over previous
//
#include <hip/hip_runtime.h>
#include <hip/hip_bf16.h>

#define NB 8
#define LQ 512
#define LK 2048
#define EE 512
#define NH 8
#define HD 64
#define NTOPK 20
#define GRP 4   // batches per score group

typedef float f4v __attribute__((ext_vector_type(4)));
typedef short s8v __attribute__((ext_vector_type(8)));
typedef __bf16 bfrag __attribute__((ext_vector_type(8)));

__device__ inline short f2bf(float f) {
    union { float f; unsigned u; } x; x.f = f;
    unsigned r = (x.u + 0x7FFFu + ((x.u >> 16) & 1u)) >> 16;
    return (short)r;
}
__device__ inline float bf2f(short s) {
    union { unsigned u; float f; } x;
    x.u = ((unsigned)(unsigned short)s) << 16;
    return x.f;
}

// one-shot f32 -> bf16 conversion of q,k,v,Wq,Wk,Wv,Wo
__global__ __launch_bounds__(256) void cvt_all(
    const float* __restrict__ q, const float* __restrict__ k, const float* __restrict__ v,
    const float* __restrict__ wq, const float* __restrict__ wk, const float* __restrict__ wv,
    const float* __restrict__ wo,
    short* __restrict__ qb, short* __restrict__ kb, short* __restrict__ vb,
    short* __restrict__ wqb, short* __restrict__ wkb, short* __restrict__ wvb,
    short* __restrict__ wob)
{
    const float* src; short* dst; int n;
    switch (blockIdx.y) {
        case 0: src = q;  dst = qb;  n = NB * LQ * EE; break;
        case 1: src = k;  dst = kb;  n = NB * LK * EE; break;
        case 2: src = v;  dst = vb;  n = NB * LK * EE; break;
        case 3: src = wq; dst = wqb; n = EE * EE; break;
        case 4: src = wk; dst = wkb; n = EE * EE; break;
        case 5: src = wv; dst = wvb; n = EE * EE; break;
        default: src = wo; dst = wob; n = EE * EE; break;
    }
    const int nv = n >> 3;
    for (int i = blockIdx.x * 256 + threadIdx.x; i < nv; i += gridDim.x * 256) {
        f4v a = *(const f4v*)&src[(size_t)i * 8];
        f4v b = *(const f4v*)&src[(size_t)i * 8 + 4];
        s8v o;
        o[0] = f2bf(a[0]); o[1] = f2bf(a[1]); o[2] = f2bf(a[2]); o[3] = f2bf(a[3]);
        o[4] = f2bf(b[0]); o[5] = f2bf(b[1]); o[6] = f2bf(b[2]); o[7] = f2bf(b[3]);
        *(s8v*)&dst[(size_t)i * 8] = o;
    }
}

// C[M][512] = A[M][512] @ W[512][512]^T, bf16 inputs.
// MODE 0: store bf16; MODE 2: store f32 + bias + resid
template<int MODE>
__global__ __launch_bounds__(256) void gemm_bf16(
    const short* __restrict__ A, const short* __restrict__ W,
    void* __restrict__ C, const float* __restrict__ bias,
    const float* __restrict__ resid)
{
    __shared__ short As[128][72];   // stride 144B -> frag reads ~2-way banks (free)
    __shared__ short Bs[128][72];
    const int tid  = threadIdx.x;
    const int lane = tid & 63;
    const int wr   = (tid >> 7) & 1;
    const int wc   = (tid >> 6) & 1;
    const size_t bm = (size_t)blockIdx.y * 128;
    const int    bn = blockIdx.x * 128;

    f4v acc[4][4] = {};
    const int lr  = lane & 15;
    const int kg  = (lane >> 4) * 8;
    const int srow = tid >> 3;
    const int sc8  = (tid & 7) * 8;

    for (int ks = 0; ks < EE; ks += 64) {
        #pragma unroll
        for (int i = 0; i < 4; i++) {
            const int row = i * 32 + srow;
            *(s8v*)&As[row][sc8] = *(const s8v*)&A[(bm + row) * EE + ks + sc8];
            *(s8v*)&Bs[row][sc8] = *(const s8v*)&W[(size_t)(bn + row) * EE + ks + sc8];
        }
        __syncthreads();
        #pragma unroll
        for (int kk = 0; kk < 64; kk += 32) {
            bfrag af[4], bf[4];
            #pragma unroll
            for (int mi = 0; mi < 4; mi++)
                af[mi] = *(const bfrag*)&As[wr * 64 + mi * 16 + lr][kk + kg];
            #pragma unroll
            for (int ni = 0; ni < 4; ni++)
                bf[ni] = *(const bfrag*)&Bs[wc * 64 + ni * 16 + lr][kk + kg];
            #pragma unroll
            for (int mi = 0; mi < 4; mi++)
                #pragma unroll
                for (int ni = 0; ni < 4; ni++)
                    acc[mi][ni] = __builtin_amdgcn_mfma_f32_16x16x32_bf16(
                        af[mi], bf[ni], acc[mi][ni], 0, 0, 0);
        }
        __syncthreads();
    }

    const int rj = (lane >> 4) * 4;
    #pragma unroll
    for (int mi = 0; mi < 4; mi++) {
        #pragma unroll
        for (int ni = 0; ni < 4; ni++) {
            const int    col  = bn + wc * 64 + ni * 16 + lr;
            const size_t row0 = bm + wr * 64 + mi * 16 + rj;
            #pragma unroll
            for (int j = 0; j < 4; j++) {
                const float  v   = acc[mi][ni][j];
                const size_t idx = (row0 + j) * EE + col;
                if (MODE == 0) ((short*)C)[idx] = f2bf(v);
                else           ((float*)C)[idx] = v + bias[col] + resid[idx];
            }
        }
    }
}

// S[z][m][n] = (1/8) * sum_k Qp[b][m][h*64+k] * Kp[b][n][h*64+k]
// z = bg*NH + h over a 4-batch group
__global__ __launch_bounds__(256) void score_gemm(
    const short* __restrict__ Qp, const short* __restrict__ Kp,
    float* __restrict__ Sg, int group)
{
    __shared__ short As[128][72];
    __shared__ short Bs[128][72];
    const int tid  = threadIdx.x;
    const int lane = tid & 63;
    const int wr   = (tid >> 7) & 1;
    const int wc   = (tid >> 6) & 1;
    const int z  = blockIdx.z;
    const int h  = z & 7;
    const int b  = group * GRP + (z >> 3);
    const int bm = blockIdx.y * 128;
    const int bn = blockIdx.x * 128;

    const short* Ab = Qp + (size_t)b * LQ * EE + h * HD;
    const short* Bb = Kp + (size_t)b * LK * EE + h * HD;

    #pragma unroll
    for (int i = 0; i < 4; i++) {
        const int row = i * 32 + (tid >> 3);
        const int c8  = (tid & 7) * 8;
        *(s8v*)&As[row][c8] = *(const s8v*)&Ab[(size_t)(bm + row) * EE + c8];
        *(s8v*)&Bs[row][c8] = *(const s8v*)&Bb[(size_t)(bn + row) * EE + c8];
    }
    __syncthreads();

    f4v acc[4][4] = {};
    const int lr = lane & 15;
    const int kg = (lane >> 4) * 8;
    #pragma unroll
    for (int kk = 0; kk < HD; kk += 32) {
        bfrag af[4], bf[4];
        #pragma unroll
        for (int mi = 0; mi < 4; mi++)
            af[mi] = *(const bfrag*)&As[wr * 64 + mi * 16 + lr][kk + kg];
        #pragma unroll
        for (int ni = 0; ni < 4; ni++)
            bf[ni] = *(const bfrag*)&Bs[wc * 64 + ni * 16 + lr][kk + kg];
        #pragma unroll
        for (int mi = 0; mi < 4; mi++)
            #pragma unroll
            for (int ni = 0; ni < 4; ni++)
                acc[mi][ni] = __builtin_amdgcn_mfma_f32_16x16x32_bf16(
                    af[mi], bf[ni], acc[mi][ni], 0, 0, 0);
    }

    float* Sh = Sg + (size_t)z * LQ * LK;
    const int rj = (lane >> 4) * 4;
    #pragma unroll
    for (int mi = 0; mi < 4; mi++) {
        #pragma unroll
        for (int ni = 0; ni < 4; ni++) {
            const int col = bn + wc * 64 + ni * 16 + lr;
            const int r0  = bm + wr * 64 + mi * 16 + rj;
            #pragma unroll
            for (int j = 0; j < 4; j++)
                Sh[(size_t)(r0 + j) * LK + col] = acc[mi][ni][j] * 0.125f;
        }
    }
}

// one wave per query row: softmax stats over 2048 keys, top-20, fused PV
__global__ __launch_bounds__(256) void topk_pv(
    const float* __restrict__ Sg, const short* __restrict__ Vp,
    short* __restrict__ attn, int group)
{
    __shared__ float sc[4][LK];
    const int lane = threadIdx.x & 63;
    const int wid  = threadIdx.x >> 6;
    const int r  = blockIdx.x * 4 + wid;     // 0..16383 within the group
    const int h  = (r >> 9) & 7;
    const int qi = r & 511;
    const int b  = group * GRP + (r >> 12);
    const float* Srow = Sg + (size_t)r * LK;

    f4v vv[8];
    float vmax = -1e30f;
    #pragma unroll
    for (int t = 0; t < 8; t++) {
        const int j = t * 256 + lane * 4;
        vv[t] = *(const f4v*)&Srow[j];
        *(f4v*)&sc[wid][j] = vv[t];
        vmax = fmaxf(vmax, fmaxf(fmaxf(vv[t][0], vv[t][1]), fmaxf(vv[t][2], vv[t][3])));
    }
    #pragma unroll
    for (int o = 32; o; o >>= 1) vmax = fmaxf(vmax, __shfl_xor(vmax, o));

    float sum = 0.f;
    #pragma unroll
    for (int t = 0; t < 8; t++)
        sum += __expf(vv[t][0] - vmax) + __expf(vv[t][1] - vmax)
             + __expf(vv[t][2] - vmax) + __expf(vv[t][3] - vmax);
    #pragma unroll
    for (int o = 32; o; o >>= 1) sum += __shfl_xor(sum, o);
    const float inv = 1.f / sum;

    float oacc = 0.f;
    const short* Vb = Vp + (size_t)b * LK * EE + h * HD + lane;
    for (int kk = 0; kk < NTOPK; kk++) {
        float bv = -1e30f; int bi = 0;
        for (int t = 0; t < 32; t++) {
            const int j = t * 64 + lane;          // conflict-free column scan
            const float v = sc[wid][j];
            if (v > bv) { bv = v; bi = j; }
        }
        #pragma unroll
        for (int o = 32; o; o >>= 1) {
            const float ov = __shfl_xor(bv, o);
            const int   oi = __shfl_xor(bi, o);
            if (ov > bv || (ov == bv && oi < bi)) { bv = ov; bi = oi; }
        }
        if ((bi & 63) == lane) sc[wid][bi] = -1e30f;   // remove winner (own column)
        const float p = __expf(bv - vmax) * inv;
        oacc += p * bf2f(Vb[(size_t)bi * EE]);
    }
    attn[((size_t)b * LQ + qi) * EE + h * HD + lane] = f2bf(oacc);
}

extern "C" void kernel_launch(void* const* d_in, const int* in_sizes, int n_in,
                              void* d_out, int out_size, void* d_ws, size_t ws_size,
                              hipStream_t stream)
{
    const float* q  = (const float*)d_in[0];
    const float* k  = (const float*)d_in[1];
    const float* v  = (const float*)d_in[2];
    const float* Wq = (const float*)d_in[3];
    const float* Wk = (const float*)d_in[4];
    const float* Wv = (const float*)d_in[5];
    const float* Wo = (const float*)d_in[6];
    const float* bo = (const float*)d_in[7];

    if (ws_size < ((size_t)208 << 20)) return;   // need 208 MiB scratch

    char*  ws  = (char*)d_ws;
    short* qb  = (short*)(ws);                        //  4 MiB bf16 [8,512,512]
    short* kb  = (short*)(ws + ((size_t)4   << 20));  // 16 MiB bf16 [8,2048,512]
    short* vb  = (short*)(ws + ((size_t)20  << 20));  // 16 MiB
    short* wqb = (short*)(ws + ((size_t)36  << 20));  // 0.5 MiB each
    short* wkb = (short*)(ws + ((size_t)36  << 20) + (512 << 10));
    short* wvb = (short*)(ws + ((size_t)37  << 20));
    short* wob = (short*)(ws + ((size_t)37  << 20) + (512 << 10));
    short* Qp  = (short*)(ws + ((size_t)38  << 20));  //  4 MiB bf16 [8,512,512]
    short* Kp  = (short*)(ws + ((size_t)42  << 20));  // 16 MiB bf16 [8,2048,512]
    short* Vp  = (short*)(ws + ((size_t)58  << 20));  // 16 MiB bf16 [8,2048,512]
    short* att = (short*)(ws + ((size_t)74  << 20));  //  4 MiB bf16 [8,512,512]
    float* Sg  = (float*)(ws + ((size_t)80  << 20));  // 128 MiB f32 [4,8,512,2048]

    dim3 blk(256);
    cvt_all<<<dim3(512, 7), blk, 0, stream>>>(q, k, v, Wq, Wk, Wv, Wo,
                                              qb, kb, vb, wqb, wkb, wvb, wob);

    gemm_bf16<0><<<dim3(4, 32),  blk, 0, stream>>>(qb, wqb, Qp, nullptr, nullptr);
    gemm_bf16<0><<<dim3(4, 128), blk, 0, stream>>>(kb, wkb, Kp, nullptr, nullptr);
    gemm_bf16<0><<<dim3(4, 128), blk, 0, stream>>>(vb, wvb, Vp, nullptr, nullptr);

    for (int g = 0; g < NB / GRP; g++) {
        score_gemm<<<dim3(LK / 128, LQ / 128, GRP * NH), blk, 0, stream>>>(Qp, Kp, Sg, g);
        topk_pv<<<dim3(GRP * NH * LQ / 4), blk, 0, stream>>>(Sg, Vp, att, g);
    }

    gemm_bf16<2><<<dim3(4, 32), blk, 0, stream>>>(att, wob, (float*)d_out, bo, q);
}

// Round 3
// 316.543 us; speedup vs baseline: 1.8789x; 1.5376x over previous
//
#include <hip/hip_runtime.h>
#include <hip/hip_bf16.h>

#define NB 8
#define LQ 512
#define LK 2048
#define EE 512
#define NH 8
#define HD 64
#define NTOPK 20
#define GRP 4   // batches per score group

typedef float f4v __attribute__((ext_vector_type(4)));
typedef short s8v __attribute__((ext_vector_type(8)));
typedef __bf16 bfrag __attribute__((ext_vector_type(8)));

__device__ inline short f2bf(float f) {
    union { float f; unsigned u; } x; x.f = f;
    unsigned r = (x.u + 0x7FFFu + ((x.u >> 16) & 1u)) >> 16;
    return (short)r;
}
__device__ inline float bf2f(short s) {
    union { unsigned u; float f; } x;
    x.u = ((unsigned)(unsigned short)s) << 16;
    return x.f;
}

// one-shot f32 -> bf16 conversion of q,k,v,Wq,Wk,Wv,Wo
__global__ __launch_bounds__(256) void cvt_all(
    const float* __restrict__ q, const float* __restrict__ k, const float* __restrict__ v,
    const float* __restrict__ wq, const float* __restrict__ wk, const float* __restrict__ wv,
    const float* __restrict__ wo,
    short* __restrict__ qb, short* __restrict__ kb, short* __restrict__ vb,
    short* __restrict__ wqb, short* __restrict__ wkb, short* __restrict__ wvb,
    short* __restrict__ wob)
{
    const float* src; short* dst; int n;
    switch (blockIdx.y) {
        case 0: src = q;  dst = qb;  n = NB * LQ * EE; break;
        case 1: src = k;  dst = kb;  n = NB * LK * EE; break;
        case 2: src = v;  dst = vb;  n = NB * LK * EE; break;
        case 3: src = wq; dst = wqb; n = EE * EE; break;
        case 4: src = wk; dst = wkb; n = EE * EE; break;
        case 5: src = wv; dst = wvb; n = EE * EE; break;
        default: src = wo; dst = wob; n = EE * EE; break;
    }
    const int nv = n >> 3;
    for (int i = blockIdx.x * 256 + threadIdx.x; i < nv; i += gridDim.x * 256) {
        f4v a = *(const f4v*)&src[(size_t)i * 8];
        f4v b = *(const f4v*)&src[(size_t)i * 8 + 4];
        s8v o;
        o[0] = f2bf(a[0]); o[1] = f2bf(a[1]); o[2] = f2bf(a[2]); o[3] = f2bf(a[3]);
        o[4] = f2bf(b[0]); o[5] = f2bf(b[1]); o[6] = f2bf(b[2]); o[7] = f2bf(b[3]);
        *(s8v*)&dst[(size_t)i * 8] = o;
    }
}

// C[M][512] = A[M][512] @ W[512][512]^T, bf16 inputs.
// MODE 0: store bf16; MODE 2: store f32 + bias + resid
template<int MODE>
__global__ __launch_bounds__(256) void gemm_bf16(
    const short* __restrict__ A, const short* __restrict__ W,
    void* __restrict__ C, const float* __restrict__ bias,
    const float* __restrict__ resid)
{
    __shared__ short As[128][72];   // stride 144B -> frag reads ~2-way banks (free)
    __shared__ short Bs[128][72];
    const int tid  = threadIdx.x;
    const int lane = tid & 63;
    const int wr   = (tid >> 7) & 1;
    const int wc   = (tid >> 6) & 1;
    const size_t bm = (size_t)blockIdx.y * 128;
    const int    bn = blockIdx.x * 128;

    f4v acc[4][4] = {};
    const int lr  = lane & 15;
    const int kg  = (lane >> 4) * 8;
    const int srow = tid >> 3;
    const int sc8  = (tid & 7) * 8;

    for (int ks = 0; ks < EE; ks += 64) {
        #pragma unroll
        for (int i = 0; i < 4; i++) {
            const int row = i * 32 + srow;
            *(s8v*)&As[row][sc8] = *(const s8v*)&A[(bm + row) * EE + ks + sc8];
            *(s8v*)&Bs[row][sc8] = *(const s8v*)&W[(size_t)(bn + row) * EE + ks + sc8];
        }
        __syncthreads();
        #pragma unroll
        for (int kk = 0; kk < 64; kk += 32) {
            bfrag af[4], bf[4];
            #pragma unroll
            for (int mi = 0; mi < 4; mi++)
                af[mi] = *(const bfrag*)&As[wr * 64 + mi * 16 + lr][kk + kg];
            #pragma unroll
            for (int ni = 0; ni < 4; ni++)
                bf[ni] = *(const bfrag*)&Bs[wc * 64 + ni * 16 + lr][kk + kg];
            #pragma unroll
            for (int mi = 0; mi < 4; mi++)
                #pragma unroll
                for (int ni = 0; ni < 4; ni++)
                    acc[mi][ni] = __builtin_amdgcn_mfma_f32_16x16x32_bf16(
                        af[mi], bf[ni], acc[mi][ni], 0, 0, 0);
        }
        __syncthreads();
    }

    const int rj = (lane >> 4) * 4;
    #pragma unroll
    for (int mi = 0; mi < 4; mi++) {
        #pragma unroll
        for (int ni = 0; ni < 4; ni++) {
            const int    col  = bn + wc * 64 + ni * 16 + lr;
            const size_t row0 = bm + wr * 64 + mi * 16 + rj;
            #pragma unroll
            for (int j = 0; j < 4; j++) {
                const float  v   = acc[mi][ni][j];
                const size_t idx = (row0 + j) * EE + col;
                if (MODE == 0) ((short*)C)[idx] = f2bf(v);
                else           ((float*)C)[idx] = v + bias[col] + resid[idx];
            }
        }
    }
}

// S[z][m][n] = (1/8) * sum_k Qp[b][m][h*64+k] * Kp[b][n][h*64+k], bf16 out
__global__ __launch_bounds__(256) void score_gemm(
    const short* __restrict__ Qp, const short* __restrict__ Kp,
    short* __restrict__ Sg, int group)
{
    __shared__ short As[128][72];
    __shared__ short Bs[128][72];
    const int tid  = threadIdx.x;
    const int lane = tid & 63;
    const int wr   = (tid >> 7) & 1;
    const int wc   = (tid >> 6) & 1;
    const int z  = blockIdx.z;
    const int h  = z & 7;
    const int b  = group * GRP + (z >> 3);
    const int bm = blockIdx.y * 128;
    const int bn = blockIdx.x * 128;

    const short* Ab = Qp + (size_t)b * LQ * EE + h * HD;
    const short* Bb = Kp + (size_t)b * LK * EE + h * HD;

    #pragma unroll
    for (int i = 0; i < 4; i++) {
        const int row = i * 32 + (tid >> 3);
        const int c8  = (tid & 7) * 8;
        *(s8v*)&As[row][c8] = *(const s8v*)&Ab[(size_t)(bm + row) * EE + c8];
        *(s8v*)&Bs[row][c8] = *(const s8v*)&Bb[(size_t)(bn + row) * EE + c8];
    }
    __syncthreads();

    f4v acc[4][4] = {};
    const int lr = lane & 15;
    const int kg = (lane >> 4) * 8;
    #pragma unroll
    for (int kk = 0; kk < HD; kk += 32) {
        bfrag af[4], bf[4];
        #pragma unroll
        for (int mi = 0; mi < 4; mi++)
            af[mi] = *(const bfrag*)&As[wr * 64 + mi * 16 + lr][kk + kg];
        #pragma unroll
        for (int ni = 0; ni < 4; ni++)
            bf[ni] = *(const bfrag*)&Bs[wc * 64 + ni * 16 + lr][kk + kg];
        #pragma unroll
        for (int mi = 0; mi < 4; mi++)
            #pragma unroll
            for (int ni = 0; ni < 4; ni++)
                acc[mi][ni] = __builtin_amdgcn_mfma_f32_16x16x32_bf16(
                    af[mi], bf[ni], acc[mi][ni], 0, 0, 0);
    }

    short* Sh = Sg + (size_t)z * LQ * LK;
    const int rj = (lane >> 4) * 4;
    #pragma unroll
    for (int mi = 0; mi < 4; mi++) {
        #pragma unroll
        for (int ni = 0; ni < 4; ni++) {
            const int col = bn + wc * 64 + ni * 16 + lr;
            const int r0  = bm + wr * 64 + mi * 16 + rj;
            #pragma unroll
            for (int j = 0; j < 4; j++)
                Sh[(size_t)(r0 + j) * LK + col] = f2bf(acc[mi][ni][j] * 0.125f);
        }
    }
}

// one wave per query row; register-resident packed-key top-20 + fused PV.
// key = mono(bf16 score) << 11 | (2047 - idx): v_max_u32 selection,
// tie-break = lowest index (matches jax.lax.top_k).
__global__ __launch_bounds__(256) void topk_pv(
    const unsigned short* __restrict__ Sg, const short* __restrict__ Vp,
    short* __restrict__ attn, int group)
{
    const int lane = threadIdx.x & 63;
    const int wid  = threadIdx.x >> 6;
    const int r  = blockIdx.x * 4 + wid;     // row within group
    const int h  = (r >> 9) & 7;
    const int qi = r & 511;
    const int b  = group * GRP + (r >> 12);
    const unsigned short* Srow = Sg + (size_t)r * LK;

    // lane holds indices idx = t*512 + lane*8 + e, t=0..3, e=0..7
    s8v raw[4];
    unsigned key[32];
    const unsigned invl = 2047u - (unsigned)(lane * 8);
    #pragma unroll
    for (int t = 0; t < 4; t++) {
        raw[t] = *(const s8v*)&Srow[t * 512 + lane * 8];
        #pragma unroll
        for (int e = 0; e < 8; e++) {
            const unsigned u = (unsigned short)raw[t][e];
            const unsigned sgn = (unsigned)((int)(u << 16) >> 31);       // -1 if negative
            const unsigned mono = u ^ (0x8000u | (sgn & 0x7FFFu));
            key[t * 8 + e] = (mono << 11) | (invl - (unsigned)(t * 512 + e));
        }
    }

    // per-lane top-2
    unsigned v1 = 0, v2 = 0;
    #pragma unroll
    for (int c = 0; c < 32; c++) {
        const unsigned kc = key[c];
        const unsigned mn = v1 < kc ? v1 : kc;
        v2 = v2 > mn ? v2 : mn;
        v1 = v1 > kc ? v1 : kc;
    }

    // wave max over v1 -> top-1 key
    unsigned K = v1;
    #pragma unroll
    for (int o = 32; o; o >>= 1) {
        const unsigned ok = __shfl_xor(K, o);
        K = K > ok ? K : ok;
    }
    // M = unpacked top score
    const unsigned mtop = K >> 11;
    const unsigned mbits = (mtop & 0x8000u) ? (mtop ^ 0x8000u) : (~mtop & 0xFFFFu);
    union { unsigned u; float f; } mu; mu.u = mbits << 16;
    const float M = mu.f;

    // denominator: sum of exp over all 2048
    float sum = 0.f;
    #pragma unroll
    for (int t = 0; t < 4; t++)
        #pragma unroll
        for (int e = 0; e < 8; e++)
            sum += __expf(bf2f(raw[t][e]) - M);
    #pragma unroll
    for (int o = 32; o; o >>= 1) sum += __shfl_xor(sum, o);
    const float inv = 1.f / sum;

    float oacc = 0.f;
    unsigned rm = 0;
    const short* Vb = Vp + (size_t)b * LK * EE + h * HD + lane;

    #pragma unroll 1
    for (int kk = 0; kk < NTOPK; kk++) {
        // process winner K (uniform across lanes)
        const unsigned idx = 2047u - (K & 2047u);
        const unsigned mo  = K >> 11;
        const unsigned sb  = (mo & 0x8000u) ? (mo ^ 0x8000u) : (~mo & 0xFFFFu);
        union { unsigned u; float f; } su; su.u = sb << 16;
        const float p = __expf(su.f - M) * inv;
        oacc += p * bf2f(Vb[(size_t)idx * EE]);

        // owner lane pops its top-1
        const bool mine = (v1 == K);
        if (mine) {
            const unsigned slot = ((idx >> 9) << 3) | (idx & 7u);
            rm |= (1u << slot);
            v1 = v2;
            v2 = 0;
        }
        // rare: owner exhausted its cached top-2 -> rescan (exec-masked, usually skipped)
        if (__any(v1 == 0u)) {
            if (v1 == 0u) {
                unsigned a1 = 0, a2 = 0;
                #pragma unroll
                for (int c = 0; c < 32; c++) {
                    const unsigned kc = (rm & (1u << c)) ? 0u : key[c];
                    const unsigned mn = a1 < kc ? a1 : kc;
                    a2 = a2 > mn ? a2 : mn;
                    a1 = a1 > kc ? a1 : kc;
                }
                v1 = a1; v2 = a2;
            }
        }
        // next winner
        K = v1;
        #pragma unroll
        for (int o = 32; o; o >>= 1) {
            const unsigned ok = __shfl_xor(K, o);
            K = K > ok ? K : ok;
        }
    }
    attn[((size_t)b * LQ + qi) * EE + h * HD + lane] = f2bf(oacc);
}

extern "C" void kernel_launch(void* const* d_in, const int* in_sizes, int n_in,
                              void* d_out, int out_size, void* d_ws, size_t ws_size,
                              hipStream_t stream)
{
    const float* q  = (const float*)d_in[0];
    const float* k  = (const float*)d_in[1];
    const float* v  = (const float*)d_in[2];
    const float* Wq = (const float*)d_in[3];
    const float* Wk = (const float*)d_in[4];
    const float* Wv = (const float*)d_in[5];
    const float* Wo = (const float*)d_in[6];
    const float* bo = (const float*)d_in[7];

    if (ws_size < ((size_t)160 << 20)) return;

    char*  ws  = (char*)d_ws;
    short* qb  = (short*)(ws);                        //  4 MiB bf16 [8,512,512]
    short* kb  = (short*)(ws + ((size_t)4   << 20));  // 16 MiB bf16 [8,2048,512]
    short* vb  = (short*)(ws + ((size_t)20  << 20));  // 16 MiB
    short* wqb = (short*)(ws + ((size_t)36  << 20));  // 0.5 MiB each
    short* wkb = (short*)(ws + ((size_t)36  << 20) + (512 << 10));
    short* wvb = (short*)(ws + ((size_t)37  << 20));
    short* wob = (short*)(ws + ((size_t)37  << 20) + (512 << 10));
    short* Qp  = (short*)(ws + ((size_t)38  << 20));  //  4 MiB bf16 [8,512,512]
    short* Kp  = (short*)(ws + ((size_t)42  << 20));  // 16 MiB bf16 [8,2048,512]
    short* Vp  = (short*)(ws + ((size_t)58  << 20));  // 16 MiB bf16 [8,2048,512]
    short* att = (short*)(ws + ((size_t)74  << 20));  //  4 MiB bf16 [8,512,512]
    short* Sg  = (short*)(ws + ((size_t)80  << 20));  // 64 MiB bf16 [4,8,512,2048]

    dim3 blk(256);
    cvt_all<<<dim3(512, 7), blk, 0, stream>>>(q, k, v, Wq, Wk, Wv, Wo,
                                              qb, kb, vb, wqb, wkb, wvb, wob);

    gemm_bf16<0><<<dim3(4, 32),  blk, 0, stream>>>(qb, wqb, Qp, nullptr, nullptr);
    gemm_bf16<0><<<dim3(4, 128), blk, 0, stream>>>(kb, wkb, Kp, nullptr, nullptr);
    gemm_bf16<0><<<dim3(4, 128), blk, 0, stream>>>(vb, wvb, Vp, nullptr, nullptr);

    for (int g = 0; g < NB / GRP; g++) {
        score_gemm<<<dim3(LK / 128, LQ / 128, GRP * NH), blk, 0, stream>>>(Qp, Kp, Sg, g);
        topk_pv<<<dim3(GRP * NH * LQ / 4), blk, 0, stream>>>((const unsigned short*)Sg, Vp, att, g);
    }

    gemm_bf16<2><<<dim3(4, 32), blk, 0, stream>>>(att, wob, (float*)d_out, bo, q);
}

// Round 5
// 290.259 us; speedup vs baseline: 2.0491x; 1.0906x over previous
//
#include <hip/hip_runtime.h>
#include <hip/hip_bf16.h>

#define NB 8
#define LQ 512
#define LK 2048
#define EE 512
#define NH 8
#define HD 64
#define NTOPK 20
#define GRP 8   // batches per score group (all of them)

typedef float f4v __attribute__((ext_vector_type(4)));
typedef short s8v __attribute__((ext_vector_type(8)));
typedef __bf16 bfrag __attribute__((ext_vector_type(8)));

__device__ inline short f2bf(float f) {
    union { float f; unsigned u; } x; x.f = f;
    unsigned r = (x.u + 0x7FFFu + ((x.u >> 16) & 1u)) >> 16;
    return (short)r;
}
__device__ inline float bf2f(short s) {
    union { unsigned u; float f; } x;
    x.u = ((unsigned)(unsigned short)s) << 16;
    return x.f;
}

// 64-lane max reduce on the VALU pipe via DPP (row_shr 1/2/4/8, bcast15, bcast31)
__device__ inline unsigned wave_max_u32(unsigned x) {
    unsigned t;
    t = (unsigned)__builtin_amdgcn_update_dpp(0, (int)x, 0x111, 0xf, 0xf, true); x = x > t ? x : t;
    t = (unsigned)__builtin_amdgcn_update_dpp(0, (int)x, 0x112, 0xf, 0xf, true); x = x > t ? x : t;
    t = (unsigned)__builtin_amdgcn_update_dpp(0, (int)x, 0x114, 0xf, 0xf, true); x = x > t ? x : t;
    t = (unsigned)__builtin_amdgcn_update_dpp(0, (int)x, 0x118, 0xf, 0xf, true); x = x > t ? x : t;
    t = (unsigned)__builtin_amdgcn_update_dpp(0, (int)x, 0x142, 0xf, 0xf, true); x = x > t ? x : t;
    t = (unsigned)__builtin_amdgcn_update_dpp(0, (int)x, 0x143, 0xf, 0xf, true); x = x > t ? x : t;
    return (unsigned)__builtin_amdgcn_readlane((int)x, 63);
}
__device__ inline float wave_sum_f32(float x) {
    union fi { float f; int i; } a, t;
    a.f = x;
    t.i = __builtin_amdgcn_update_dpp(0, a.i, 0x111, 0xf, 0xf, true); a.f += t.f;
    t.i = __builtin_amdgcn_update_dpp(0, a.i, 0x112, 0xf, 0xf, true); a.f += t.f;
    t.i = __builtin_amdgcn_update_dpp(0, a.i, 0x114, 0xf, 0xf, true); a.f += t.f;
    t.i = __builtin_amdgcn_update_dpp(0, a.i, 0x118, 0xf, 0xf, true); a.f += t.f;
    t.i = __builtin_amdgcn_update_dpp(0, a.i, 0x142, 0xf, 0xf, true); a.f += t.f;
    t.i = __builtin_amdgcn_update_dpp(0, a.i, 0x143, 0xf, 0xf, true); a.f += t.f;
    a.i = __builtin_amdgcn_readlane(a.i, 63);
    return a.f;
}

// one-shot f32 -> bf16 conversion of q,k,v,Wq,Wk,Wv,Wo
__global__ __launch_bounds__(256) void cvt_all(
    const float* __restrict__ q, const float* __restrict__ k, const float* __restrict__ v,
    const float* __restrict__ wq, const float* __restrict__ wk, const float* __restrict__ wv,
    const float* __restrict__ wo,
    short* __restrict__ qb, short* __restrict__ kb, short* __restrict__ vb,
    short* __restrict__ wqb, short* __restrict__ wkb, short* __restrict__ wvb,
    short* __restrict__ wob)
{
    const float* src; short* dst; int n;
    switch (blockIdx.y) {
        case 0: src = q;  dst = qb;  n = NB * LQ * EE; break;
        case 1: src = k;  dst = kb;  n = NB * LK * EE; break;
        case 2: src = v;  dst = vb;  n = NB * LK * EE; break;
        case 3: src = wq; dst = wqb; n = EE * EE; break;
        case 4: src = wk; dst = wkb; n = EE * EE; break;
        case 5: src = wv; dst = wvb; n = EE * EE; break;
        default: src = wo; dst = wob; n = EE * EE; break;
    }
    const int nv = n >> 3;
    for (int i = blockIdx.x * 256 + threadIdx.x; i < nv; i += gridDim.x * 256) {
        f4v a = *(const f4v*)&src[(size_t)i * 8];
        f4v b = *(const f4v*)&src[(size_t)i * 8 + 4];
        s8v o;
        o[0] = f2bf(a[0]); o[1] = f2bf(a[1]); o[2] = f2bf(a[2]); o[3] = f2bf(a[3]);
        o[4] = f2bf(b[0]); o[5] = f2bf(b[1]); o[6] = f2bf(b[2]); o[7] = f2bf(b[3]);
        *(s8v*)&dst[(size_t)i * 8] = o;
    }
}

// C[M][512] = A[M][512] @ W[512][512]^T, bf16 inputs.
// MODE 0: store bf16; MODE 2: store f32 + bias + resid
template<int MODE>
__global__ __launch_bounds__(256) void gemm_bf16(
    const short* __restrict__ A, const short* __restrict__ W,
    void* __restrict__ C, const float* __restrict__ bias,
    const float* __restrict__ resid)
{
    __shared__ short As[128][72];
    __shared__ short Bs[128][72];
    const int tid  = threadIdx.x;
    const int lane = tid & 63;
    const int wr   = (tid >> 7) & 1;
    const int wc   = (tid >> 6) & 1;
    const size_t bm = (size_t)blockIdx.y * 128;
    const int    bn = blockIdx.x * 128;

    f4v acc[4][4] = {};
    const int lr  = lane & 15;
    const int kg  = (lane >> 4) * 8;
    const int srow = tid >> 3;
    const int sc8  = (tid & 7) * 8;

    for (int ks = 0; ks < EE; ks += 64) {
        #pragma unroll
        for (int i = 0; i < 4; i++) {
            const int row = i * 32 + srow;
            *(s8v*)&As[row][sc8] = *(const s8v*)&A[(bm + row) * EE + ks + sc8];
            *(s8v*)&Bs[row][sc8] = *(const s8v*)&W[(size_t)(bn + row) * EE + ks + sc8];
        }
        __syncthreads();
        #pragma unroll
        for (int kk = 0; kk < 64; kk += 32) {
            bfrag af[4], bf[4];
            #pragma unroll
            for (int mi = 0; mi < 4; mi++)
                af[mi] = *(const bfrag*)&As[wr * 64 + mi * 16 + lr][kk + kg];
            #pragma unroll
            for (int ni = 0; ni < 4; ni++)
                bf[ni] = *(const bfrag*)&Bs[wc * 64 + ni * 16 + lr][kk + kg];
            #pragma unroll
            for (int mi = 0; mi < 4; mi++)
                #pragma unroll
                for (int ni = 0; ni < 4; ni++)
                    acc[mi][ni] = __builtin_amdgcn_mfma_f32_16x16x32_bf16(
                        af[mi], bf[ni], acc[mi][ni], 0, 0, 0);
        }
        __syncthreads();
    }

    const int rj = (lane >> 4) * 4;
    #pragma unroll
    for (int mi = 0; mi < 4; mi++) {
        #pragma unroll
        for (int ni = 0; ni < 4; ni++) {
            const int    col  = bn + wc * 64 + ni * 16 + lr;
            const size_t row0 = bm + wr * 64 + mi * 16 + rj;
            #pragma unroll
            for (int j = 0; j < 4; j++) {
                const float  v   = acc[mi][ni][j];
                const size_t idx = (row0 + j) * EE + col;
                if (MODE == 0) ((short*)C)[idx] = f2bf(v);
                else           ((float*)C)[idx] = v + bias[col] + resid[idx];
            }
        }
    }
}

// S[z][m][n] = (1/8) * sum_k Qp[b][m][h*64+k] * Kp[b][n][h*64+k], bf16 out, z=b*8+h
__global__ __launch_bounds__(256) void score_gemm(
    const short* __restrict__ Qp, const short* __restrict__ Kp,
    short* __restrict__ Sg)
{
    __shared__ short As[128][72];
    __shared__ short Bs[128][72];
    const int tid  = threadIdx.x;
    const int lane = tid & 63;
    const int wr   = (tid >> 7) & 1;
    const int wc   = (tid >> 6) & 1;
    const int z  = blockIdx.z;
    const int h  = z & 7;
    const int b  = z >> 3;
    const int bm = blockIdx.y * 128;
    const int bn = blockIdx.x * 128;

    const short* Ab = Qp + (size_t)b * LQ * EE + h * HD;
    const short* Bb = Kp + (size_t)b * LK * EE + h * HD;

    #pragma unroll
    for (int i = 0; i < 4; i++) {
        const int row = i * 32 + (tid >> 3);
        const int c8  = (tid & 7) * 8;
        *(s8v*)&As[row][c8] = *(const s8v*)&Ab[(size_t)(bm + row) * EE + c8];
        *(s8v*)&Bs[row][c8] = *(const s8v*)&Bb[(size_t)(bn + row) * EE + c8];
    }
    __syncthreads();

    f4v acc[4][4] = {};
    const int lr = lane & 15;
    const int kg = (lane >> 4) * 8;
    #pragma unroll
    for (int kk = 0; kk < HD; kk += 32) {
        bfrag af[4], bf[4];
        #pragma unroll
        for (int mi = 0; mi < 4; mi++)
            af[mi] = *(const bfrag*)&As[wr * 64 + mi * 16 + lr][kk + kg];
        #pragma unroll
        for (int ni = 0; ni < 4; ni++)
            bf[ni] = *(const bfrag*)&Bs[wc * 64 + ni * 16 + lr][kk + kg];
        #pragma unroll
        for (int mi = 0; mi < 4; mi++)
            #pragma unroll
            for (int ni = 0; ni < 4; ni++)
                acc[mi][ni] = __builtin_amdgcn_mfma_f32_16x16x32_bf16(
                    af[mi], bf[ni], acc[mi][ni], 0, 0, 0);
    }

    short* Sh = Sg + (size_t)z * LQ * LK;
    const int rj = (lane >> 4) * 4;
    #pragma unroll
    for (int mi = 0; mi < 4; mi++) {
        #pragma unroll
        for (int ni = 0; ni < 4; ni++) {
            const int col = bn + wc * 64 + ni * 16 + lr;
            const int r0  = bm + wr * 64 + mi * 16 + rj;
            #pragma unroll
            for (int j = 0; j < 4; j++)
                Sh[(size_t)(r0 + j) * LK + col] = f2bf(acc[mi][ni][j] * 0.125f);
        }
    }
}

// one wave per query row; packed-key top-20 via DPP max-reduce, then ILP PV.
// key = mono(bf16 score) << 11 | (2047 - idx): v_max_u32 selection,
// tie-break = lowest index (matches jax.lax.top_k).
__global__ __launch_bounds__(256) void topk_pv(
    const unsigned short* __restrict__ Sg, const short* __restrict__ Vp,
    short* __restrict__ attn)
{
    __shared__ float    wp[4][NTOPK];
    __shared__ unsigned widx[4][NTOPK];
    const int lane = threadIdx.x & 63;
    const int wid  = threadIdx.x >> 6;
    const int r  = blockIdx.x * 4 + wid;     // 0..32767
    const int h  = (r >> 9) & 7;
    const int qi = r & 511;
    const int b  = r >> 12;
    const unsigned short* Srow = Sg + (size_t)r * LK;

    // lane holds indices idx = t*512 + lane*8 + e
    s8v raw[4];
    #pragma unroll
    for (int t = 0; t < 4; t++)
        raw[t] = *(const s8v*)&Srow[t * 512 + lane * 8];

    // fused key-build + per-lane top-2 (keys NOT kept: rescan rebuilds from raw)
    const unsigned invl = 2047u - (unsigned)(lane * 8);
    unsigned v1 = 0, v2 = 0;
    #pragma unroll
    for (int t = 0; t < 4; t++) {
        #pragma unroll
        for (int e = 0; e < 8; e++) {
            const unsigned u   = (unsigned short)raw[t][e];
            const unsigned sgn = (unsigned)((int)(u << 16) >> 31);
            const unsigned kc  = ((u ^ (0x8000u | (sgn & 0x7FFFu))) << 11)
                               | (invl - (unsigned)(t * 512 + e));
            const unsigned mn = v1 < kc ? v1 : kc;
            v2 = v2 > mn ? v2 : mn;
            v1 = v1 > kc ? v1 : kc;
        }
    }

    // global top-1 -> M
    unsigned K = wave_max_u32(v1);
    {
        const unsigned mtop  = K >> 11;
        const unsigned mbits = (mtop & 0x8000u) ? (mtop ^ 0x8000u) : (~mtop & 0xFFFFu);
        union { unsigned u; float f; } mu; mu.u = mbits << 16;
        const float M = mu.f;

        // denominator over all 2048
        float sum = 0.f;
        #pragma unroll
        for (int t = 0; t < 4; t++)
            #pragma unroll
            for (int e = 0; e < 8; e++)
                sum += __expf(bf2f(raw[t][e]) - M);
        sum = wave_sum_f32(sum);
        const float inv = 1.f / sum;

        unsigned rm = 0;
        #pragma unroll 1
        for (int kk = 0; kk < NTOPK; kk++) {
            const unsigned idx = 2047u - (K & 2047u);
            const unsigned mo  = K >> 11;
            const unsigned sb  = (mo & 0x8000u) ? (mo ^ 0x8000u) : (~mo & 0xFFFFu);
            union { unsigned u; float f; } su; su.u = sb << 16;
            if (lane == 0) {
                wp[wid][kk]   = __expf(su.f - M) * inv;
                widx[wid][kk] = idx;
            }
            if (v1 == K) {                       // unique owner (index in key)
                const unsigned slot = ((idx >> 9) << 3) | (idx & 7u);
                rm |= (1u << slot);
                v1 = v2; v2 = 0;
            }
            if (__any(v1 == 0u)) {               // rare: rebuild owner's top-2
                if (v1 == 0u) {
                    unsigned a1 = 0, a2 = 0;
                    #pragma unroll
                    for (int t = 0; t < 4; t++) {
                        #pragma unroll
                        for (int e = 0; e < 8; e++) {
                            const int c = t * 8 + e;
                            const unsigned u   = (unsigned short)raw[t][e];
                            const unsigned sgn = (unsigned)((int)(u << 16) >> 31);
                            unsigned kc = ((u ^ (0x8000u | (sgn & 0x7FFFu))) << 11)
                                        | (invl - (unsigned)(t * 512 + e));
                            kc = ((rm >> c) & 1u) ? 0u : kc;
                            const unsigned mn = a1 < kc ? a1 : kc;
                            a2 = a2 > mn ? a2 : mn;
                            a1 = a1 > kc ? a1 : kc;
                        }
                    }
                    v1 = a1; v2 = a2;
                }
            }
            K = wave_max_u32(v1);
        }
    }

    // PV: 20 independent gathers (single latency), p/idx via LDS broadcast reads
    float oacc = 0.f;
    const short* Vb = Vp + (size_t)b * LK * EE + h * HD + lane;
    #pragma unroll
    for (int kk = 0; kk < NTOPK; kk++)
        oacc += wp[wid][kk] * bf2f(Vb[(size_t)widx[wid][kk] * EE]);

    attn[((size_t)b * LQ + qi) * EE + h * HD + lane] = f2bf(oacc);
}

extern "C" void kernel_launch(void* const* d_in, const int* in_sizes, int n_in,
                              void* d_out, int out_size, void* d_ws, size_t ws_size,
                              hipStream_t stream)
{
    const float* q  = (const float*)d_in[0];
    const float* k  = (const float*)d_in[1];
    const float* v  = (const float*)d_in[2];
    const float* Wq = (const float*)d_in[3];
    const float* Wk = (const float*)d_in[4];
    const float* Wv = (const float*)d_in[5];
    const float* Wo = (const float*)d_in[6];
    const float* bo = (const float*)d_in[7];

    if (ws_size < ((size_t)208 << 20)) return;

    char*  ws  = (char*)d_ws;
    short* qb  = (short*)(ws);                        //  4 MiB bf16 [8,512,512]
    short* kb  = (short*)(ws + ((size_t)4   << 20));  // 16 MiB bf16 [8,2048,512]
    short* vb  = (short*)(ws + ((size_t)20  << 20));  // 16 MiB
    short* wqb = (short*)(ws + ((size_t)36  << 20));  // 0.5 MiB each
    short* wkb = (short*)(ws + ((size_t)36  << 20) + (512 << 10));
    short* wvb = (short*)(ws + ((size_t)37  << 20));
    short* wob = (short*)(ws + ((size_t)37  << 20) + (512 << 10));
    short* Qp  = (short*)(ws + ((size_t)38  << 20));  //  4 MiB bf16 [8,512,512]
    short* Kp  = (short*)(ws + ((size_t)42  << 20));  // 16 MiB bf16 [8,2048,512]
    short* Vp  = (short*)(ws + ((size_t)58  << 20));  // 16 MiB bf16 [8,2048,512]
    short* att = (short*)(ws + ((size_t)74  << 20));  //  4 MiB bf16 [8,512,512]
    short* Sg  = (short*)(ws + ((size_t)80  << 20));  // 128 MiB bf16 [8,8,512,2048]

    dim3 blk(256);
    cvt_all<<<dim3(512, 7), blk, 0, stream>>>(q, k, v, Wq, Wk, Wv, Wo,
                                              qb, kb, vb, wqb, wkb, wvb, wob);

    gemm_bf16<0><<<dim3(4, 32),  blk, 0, stream>>>(qb, wqb, Qp, nullptr, nullptr);
    gemm_bf16<0><<<dim3(4, 128), blk, 0, stream>>>(kb, wkb, Kp, nullptr, nullptr);
    gemm_bf16<0><<<dim3(4, 128), blk, 0, stream>>>(vb, wvb, Vp, nullptr, nullptr);

    score_gemm<<<dim3(LK / 128, LQ / 128, NB * NH), blk, 0, stream>>>(Qp, Kp, Sg);
    topk_pv<<<dim3(NB * NH * LQ / 4), blk, 0, stream>>>((const unsigned short*)Sg, Vp, att);

    gemm_bf16<2><<<dim3(4, 32), blk, 0, stream>>>(att, wob, (float*)d_out, bo, q);
}

// Round 6
// 271.804 us; speedup vs baseline: 2.1882x; 1.0679x over previous
//
#include <hip/hip_runtime.h>
#include <hip/hip_bf16.h>

#define NB 8
#define LQ 512
#define LK 2048
#define EE 512
#define NH 8
#define HD 64
#define NTOPK 20

typedef float f4v __attribute__((ext_vector_type(4)));
typedef short s8v __attribute__((ext_vector_type(8)));
typedef __bf16 bfrag __attribute__((ext_vector_type(8)));

__device__ inline short f2bf(float f) {
    union { float f; unsigned u; } x; x.f = f;
    unsigned r = (x.u + 0x7FFFu + ((x.u >> 16) & 1u)) >> 16;
    return (short)r;
}
__device__ inline float bf2f(short s) {
    union { unsigned u; float f; } x;
    x.u = ((unsigned)(unsigned short)s) << 16;
    return x.f;
}
__device__ inline float exp2_fast(float x) {   // bare v_exp_f32 (2^x)
    float r;
    asm("v_exp_f32 %0, %1" : "=v"(r) : "v"(x));
    return r;
}

// 64-lane max reduce on the VALU pipe via DPP (row_shr 1/2/4/8, bcast15, bcast31)
__device__ inline unsigned wave_max_u32(unsigned x) {
    unsigned t;
    t = (unsigned)__builtin_amdgcn_update_dpp(0, (int)x, 0x111, 0xf, 0xf, true); x = x > t ? x : t;
    t = (unsigned)__builtin_amdgcn_update_dpp(0, (int)x, 0x112, 0xf, 0xf, true); x = x > t ? x : t;
    t = (unsigned)__builtin_amdgcn_update_dpp(0, (int)x, 0x114, 0xf, 0xf, true); x = x > t ? x : t;
    t = (unsigned)__builtin_amdgcn_update_dpp(0, (int)x, 0x118, 0xf, 0xf, true); x = x > t ? x : t;
    t = (unsigned)__builtin_amdgcn_update_dpp(0, (int)x, 0x142, 0xf, 0xf, true); x = x > t ? x : t;
    t = (unsigned)__builtin_amdgcn_update_dpp(0, (int)x, 0x143, 0xf, 0xf, true); x = x > t ? x : t;
    return (unsigned)__builtin_amdgcn_readlane((int)x, 63);
}
__device__ inline float wave_sum_f32(float x) {
    union fi { float f; int i; } a, t;
    a.f = x;
    t.i = __builtin_amdgcn_update_dpp(0, a.i, 0x111, 0xf, 0xf, true); a.f += t.f;
    t.i = __builtin_amdgcn_update_dpp(0, a.i, 0x112, 0xf, 0xf, true); a.f += t.f;
    t.i = __builtin_amdgcn_update_dpp(0, a.i, 0x114, 0xf, 0xf, true); a.f += t.f;
    t.i = __builtin_amdgcn_update_dpp(0, a.i, 0x118, 0xf, 0xf, true); a.f += t.f;
    t.i = __builtin_amdgcn_update_dpp(0, a.i, 0x142, 0xf, 0xf, true); a.f += t.f;
    t.i = __builtin_amdgcn_update_dpp(0, a.i, 0x143, 0xf, 0xf, true); a.f += t.f;
    a.i = __builtin_amdgcn_readlane(a.i, 63);
    return a.f;
}

// one-shot f32 -> bf16 conversion of q,k,v,Wq,Wk,Wv,Wo
__global__ __launch_bounds__(256) void cvt_all(
    const float* __restrict__ q, const float* __restrict__ k, const float* __restrict__ v,
    const float* __restrict__ wq, const float* __restrict__ wk, const float* __restrict__ wv,
    const float* __restrict__ wo,
    short* __restrict__ qb, short* __restrict__ kb, short* __restrict__ vb,
    short* __restrict__ wqb, short* __restrict__ wkb, short* __restrict__ wvb,
    short* __restrict__ wob)
{
    const float* src; short* dst; int n;
    switch (blockIdx.y) {
        case 0: src = q;  dst = qb;  n = NB * LQ * EE; break;
        case 1: src = k;  dst = kb;  n = NB * LK * EE; break;
        case 2: src = v;  dst = vb;  n = NB * LK * EE; break;
        case 3: src = wq; dst = wqb; n = EE * EE; break;
        case 4: src = wk; dst = wkb; n = EE * EE; break;
        case 5: src = wv; dst = wvb; n = EE * EE; break;
        default: src = wo; dst = wob; n = EE * EE; break;
    }
    const int nv = n >> 3;
    for (int i = blockIdx.x * 256 + threadIdx.x; i < nv; i += gridDim.x * 256) {
        f4v a = *(const f4v*)&src[(size_t)i * 8];
        f4v b = *(const f4v*)&src[(size_t)i * 8 + 4];
        s8v o;
        o[0] = f2bf(a[0]); o[1] = f2bf(a[1]); o[2] = f2bf(a[2]); o[3] = f2bf(a[3]);
        o[4] = f2bf(b[0]); o[5] = f2bf(b[1]); o[6] = f2bf(b[2]); o[7] = f2bf(b[3]);
        *(s8v*)&dst[(size_t)i * 8] = o;
    }
}

// C[M][512] = A[M][512] @ W[512][512]^T, bf16 inputs.
// MODE 0: store bf16; MODE 2: store f32 + bias + resid
template<int MODE>
__global__ __launch_bounds__(256) void gemm_bf16(
    const short* __restrict__ A, const short* __restrict__ W,
    void* __restrict__ C, const float* __restrict__ bias,
    const float* __restrict__ resid)
{
    __shared__ short As[128][72];
    __shared__ short Bs[128][72];
    const int tid  = threadIdx.x;
    const int lane = tid & 63;
    const int wr   = (tid >> 7) & 1;
    const int wc   = (tid >> 6) & 1;
    const size_t bm = (size_t)blockIdx.y * 128;
    const int    bn = blockIdx.x * 128;

    f4v acc[4][4] = {};
    const int lr  = lane & 15;
    const int kg  = (lane >> 4) * 8;
    const int srow = tid >> 3;
    const int sc8  = (tid & 7) * 8;

    for (int ks = 0; ks < EE; ks += 64) {
        #pragma unroll
        for (int i = 0; i < 4; i++) {
            const int row = i * 32 + srow;
            *(s8v*)&As[row][sc8] = *(const s8v*)&A[(bm + row) * EE + ks + sc8];
            *(s8v*)&Bs[row][sc8] = *(const s8v*)&W[(size_t)(bn + row) * EE + ks + sc8];
        }
        __syncthreads();
        #pragma unroll
        for (int kk = 0; kk < 64; kk += 32) {
            bfrag af[4], bf[4];
            #pragma unroll
            for (int mi = 0; mi < 4; mi++)
                af[mi] = *(const bfrag*)&As[wr * 64 + mi * 16 + lr][kk + kg];
            #pragma unroll
            for (int ni = 0; ni < 4; ni++)
                bf[ni] = *(const bfrag*)&Bs[wc * 64 + ni * 16 + lr][kk + kg];
            #pragma unroll
            for (int mi = 0; mi < 4; mi++)
                #pragma unroll
                for (int ni = 0; ni < 4; ni++)
                    acc[mi][ni] = __builtin_amdgcn_mfma_f32_16x16x32_bf16(
                        af[mi], bf[ni], acc[mi][ni], 0, 0, 0);
        }
        __syncthreads();
    }

    const int rj = (lane >> 4) * 4;
    #pragma unroll
    for (int mi = 0; mi < 4; mi++) {
        #pragma unroll
        for (int ni = 0; ni < 4; ni++) {
            const int    col  = bn + wc * 64 + ni * 16 + lr;
            const size_t row0 = bm + wr * 64 + mi * 16 + rj;
            #pragma unroll
            for (int j = 0; j < 4; j++) {
                const float  v   = acc[mi][ni][j];
                const size_t idx = (row0 + j) * EE + col;
                if (MODE == 0) ((short*)C)[idx] = f2bf(v);
                else           ((float*)C)[idx] = v + bias[col] + resid[idx];
            }
        }
    }
}

// S'[z][m][n] = (log2e/8) * sum_k Qp[b][m][h*64+k] * Kp[b][n][h*64+k], bf16, z=b*8+h
// (scores pre-scaled into the exp2 domain so softmax uses bare v_exp_f32)
__global__ __launch_bounds__(256) void score_gemm(
    const short* __restrict__ Qp, const short* __restrict__ Kp,
    short* __restrict__ Sg)
{
    __shared__ short As[128][72];
    __shared__ short Bs[128][72];
    const int tid  = threadIdx.x;
    const int lane = tid & 63;
    const int wr   = (tid >> 7) & 1;
    const int wc   = (tid >> 6) & 1;
    const int z  = blockIdx.z;
    const int h  = z & 7;
    const int b  = z >> 3;
    const int bm = blockIdx.y * 128;
    const int bn = blockIdx.x * 128;

    const short* Ab = Qp + (size_t)b * LQ * EE + h * HD;
    const short* Bb = Kp + (size_t)b * LK * EE + h * HD;

    #pragma unroll
    for (int i = 0; i < 4; i++) {
        const int row = i * 32 + (tid >> 3);
        const int c8  = (tid & 7) * 8;
        *(s8v*)&As[row][c8] = *(const s8v*)&Ab[(size_t)(bm + row) * EE + c8];
        *(s8v*)&Bs[row][c8] = *(const s8v*)&Bb[(size_t)(bn + row) * EE + c8];
    }
    __syncthreads();

    f4v acc[4][4] = {};
    const int lr = lane & 15;
    const int kg = (lane >> 4) * 8;
    #pragma unroll
    for (int kk = 0; kk < HD; kk += 32) {
        bfrag af[4], bf[4];
        #pragma unroll
        for (int mi = 0; mi < 4; mi++)
            af[mi] = *(const bfrag*)&As[wr * 64 + mi * 16 + lr][kk + kg];
        #pragma unroll
        for (int ni = 0; ni < 4; ni++)
            bf[ni] = *(const bfrag*)&Bs[wc * 64 + ni * 16 + lr][kk + kg];
        #pragma unroll
        for (int mi = 0; mi < 4; mi++)
            #pragma unroll
            for (int ni = 0; ni < 4; ni++)
                acc[mi][ni] = __builtin_amdgcn_mfma_f32_16x16x32_bf16(
                    af[mi], bf[ni], acc[mi][ni], 0, 0, 0);
    }

    short* Sh = Sg + (size_t)z * LQ * LK;
    const int rj = (lane >> 4) * 4;
    #pragma unroll
    for (int mi = 0; mi < 4; mi++) {
        #pragma unroll
        for (int ni = 0; ni < 4; ni++) {
            const int col = bn + wc * 64 + ni * 16 + lr;
            const int r0  = bm + wr * 64 + mi * 16 + rj;
            #pragma unroll
            for (int j = 0; j < 4; j++)
                Sh[(size_t)(r0 + j) * LK + col] = f2bf(acc[mi][ni][j] * 0.18033688f);
        }
    }
}

// one wave per query row; packed-key top-20 (per-lane top-3 + DPP max), deferred
// unpack, fused PV. key = mono(bf16 score') << 11 | (2047 - idx): selection is
// v_max_u32, tie-break = lowest index (matches jax.lax.top_k).
__global__ __launch_bounds__(256) void topk_pv(
    const unsigned short* __restrict__ Sg, const short* __restrict__ Vp,
    short* __restrict__ attn)
{
    __shared__ unsigned wkey[4][NTOPK];
    __shared__ float    wp[4][NTOPK];
    __shared__ unsigned widx[4][NTOPK];
    const int lane = threadIdx.x & 63;
    const int wid  = threadIdx.x >> 6;
    const int r  = blockIdx.x * 4 + wid;     // 0..32767
    const int h  = (r >> 9) & 7;
    const int qi = r & 511;
    const int b  = r >> 12;
    const unsigned short* Srow = Sg + (size_t)r * LK;

    // lane holds indices idx = t*512 + lane*8 + e
    s8v raw[4];
    #pragma unroll
    for (int t = 0; t < 4; t++)
        raw[t] = *(const s8v*)&Srow[t * 512 + lane * 8];

    // fused key-build + per-lane sorted top-3 (keys rebuilt from raw on rare rescan)
    const unsigned invl = 2047u - (unsigned)(lane * 8);
    unsigned v1 = 0, v2 = 0, v3 = 0;
    #pragma unroll
    for (int t = 0; t < 4; t++) {
        #pragma unroll
        for (int e = 0; e < 8; e++) {
            const unsigned u   = (unsigned short)raw[t][e];
            const unsigned sgn = (unsigned)((int)(u << 16) >> 31);
            const unsigned kc  = ((u ^ (0x8000u | (sgn & 0x7FFFu))) << 11)
                               | (invl - (unsigned)(t * 512 + e));
            const unsigned m1 = v1 < kc ? v1 : kc;
            v1 = v1 > kc ? v1 : kc;
            const unsigned m2 = v2 < m1 ? v2 : m1;
            v2 = v2 > m1 ? v2 : m1;
            v3 = v3 > m2 ? v3 : m2;
        }
    }

    // global top-1 -> M (exp2-domain max)
    unsigned K = wave_max_u32(v1);
    const unsigned mtop  = K >> 11;
    const unsigned mbits = (mtop & 0x8000u) ? (mtop ^ 0x8000u) : (~mtop & 0xFFFFu);
    union { unsigned u; float f; } mu; mu.u = mbits << 16;
    const float M = mu.f;

    // denominator over all 2048: sum of 2^(s' - M)
    float sum = 0.f;
    #pragma unroll
    for (int t = 0; t < 4; t++)
        #pragma unroll
        for (int e = 0; e < 8; e++)
            sum += exp2_fast(bf2f(raw[t][e]) - M);
    sum = wave_sum_f32(sum);
    const float inv = 1.f / sum;

    // selection loop: store packed key only; pop owner; rare top-3 rebuild
    unsigned rm = 0;
    #pragma unroll 1
    for (int kk = 0; kk < NTOPK; kk++) {
        if (lane == 0) wkey[wid][kk] = K;
        if (v1 == K) {                       // unique owner (index embedded in key)
            const unsigned idx  = 2047u - (K & 2047u);
            const unsigned slot = ((idx >> 9) << 3) | (idx & 7u);
            rm |= (1u << slot);
            v1 = v2; v2 = v3; v3 = 0;
        }
        if (__any(v1 == 0u)) {               // rare (~0.3/wave): rebuild owner's top-3
            if (v1 == 0u) {
                unsigned a1 = 0, a2 = 0, a3 = 0;
                #pragma unroll
                for (int t = 0; t < 4; t++) {
                    #pragma unroll
                    for (int e = 0; e < 8; e++) {
                        const int c = t * 8 + e;
                        const unsigned u   = (unsigned short)raw[t][e];
                        const unsigned sgn = (unsigned)((int)(u << 16) >> 31);
                        unsigned kc = ((u ^ (0x8000u | (sgn & 0x7FFFu))) << 11)
                                    | (invl - (unsigned)(t * 512 + e));
                        kc = ((rm >> c) & 1u) ? 0u : kc;
                        const unsigned m1 = a1 < kc ? a1 : kc;
                        a1 = a1 > kc ? a1 : kc;
                        const unsigned m2 = a2 < m1 ? a2 : m1;
                        a2 = a2 > m1 ? a2 : m1;
                        a3 = a3 > m2 ? a3 : m2;
                    }
                }
                v1 = a1; v2 = a2; v3 = a3;
            }
        }
        K = wave_max_u32(v1);
    }

    // parallel unpack: lanes 0..19 each decode one winner
    __syncthreads();
    if (lane < NTOPK) {
        const unsigned Kk  = wkey[wid][lane];
        const unsigned idx = 2047u - (Kk & 2047u);
        const unsigned mo  = Kk >> 11;
        const unsigned sb  = (mo & 0x8000u) ? (mo ^ 0x8000u) : (~mo & 0xFFFFu);
        union { unsigned u; float f; } su; su.u = sb << 16;
        wp[wid][lane]   = exp2_fast(su.f - M) * inv;
        widx[wid][lane] = idx;
    }
    __syncthreads();

    // PV: 20 independent gathers (single latency), p/idx via LDS broadcast reads
    float oacc = 0.f;
    const short* Vb = Vp + (size_t)b * LK * EE + h * HD + lane;
    #pragma unroll
    for (int kk = 0; kk < NTOPK; kk++)
        oacc += wp[wid][kk] * bf2f(Vb[(size_t)widx[wid][kk] * EE]);

    attn[((size_t)b * LQ + qi) * EE + h * HD + lane] = f2bf(oacc);
}

extern "C" void kernel_launch(void* const* d_in, const int* in_sizes, int n_in,
                              void* d_out, int out_size, void* d_ws, size_t ws_size,
                              hipStream_t stream)
{
    const float* q  = (const float*)d_in[0];
    const float* k  = (const float*)d_in[1];
    const float* v  = (const float*)d_in[2];
    const float* Wq = (const float*)d_in[3];
    const float* Wk = (const float*)d_in[4];
    const float* Wv = (const float*)d_in[5];
    const float* Wo = (const float*)d_in[6];
    const float* bo = (const float*)d_in[7];

    if (ws_size < ((size_t)208 << 20)) return;

    char*  ws  = (char*)d_ws;
    short* qb  = (short*)(ws);                        //  4 MiB bf16 [8,512,512]
    short* kb  = (short*)(ws + ((size_t)4   << 20));  // 16 MiB bf16 [8,2048,512]
    short* vb  = (short*)(ws + ((size_t)20  << 20));  // 16 MiB
    short* wqb = (short*)(ws + ((size_t)36  << 20));  // 0.5 MiB each
    short* wkb = (short*)(ws + ((size_t)36  << 20) + (512 << 10));
    short* wvb = (short*)(ws + ((size_t)37  << 20));
    short* wob = (short*)(ws + ((size_t)37  << 20) + (512 << 10));
    short* Qp  = (short*)(ws + ((size_t)38  << 20));  //  4 MiB bf16 [8,512,512]
    short* Kp  = (short*)(ws + ((size_t)42  << 20));  // 16 MiB bf16 [8,2048,512]
    short* Vp  = (short*)(ws + ((size_t)58  << 20));  // 16 MiB bf16 [8,2048,512]
    short* att = (short*)(ws + ((size_t)74  << 20));  //  4 MiB bf16 [8,512,512]
    short* Sg  = (short*)(ws + ((size_t)80  << 20));  // 128 MiB bf16 [8,8,512,2048]

    dim3 blk(256);
    cvt_all<<<dim3(512, 7), blk, 0, stream>>>(q, k, v, Wq, Wk, Wv, Wo,
                                              qb, kb, vb, wqb, wkb, wvb, wob);

    gemm_bf16<0><<<dim3(4, 32),  blk, 0, stream>>>(qb, wqb, Qp, nullptr, nullptr);
    gemm_bf16<0><<<dim3(4, 128), blk, 0, stream>>>(kb, wkb, Kp, nullptr, nullptr);
    gemm_bf16<0><<<dim3(4, 128), blk, 0, stream>>>(vb, wvb, Vp, nullptr, nullptr);

    score_gemm<<<dim3(LK / 128, LQ / 128, NB * NH), blk, 0, stream>>>(Qp, Kp, Sg);
    topk_pv<<<dim3(NB * NH * LQ / 4), blk, 0, stream>>>((const unsigned short*)Sg, Vp, att);

    gemm_bf16<2><<<dim3(4, 32), blk, 0, stream>>>(att, wob, (float*)d_out, bo, q);
}